// Round 14
// baseline (248.800 us; speedup 1.0000x reference)
//
#include <hip/hip_runtime.h>
#include <hip/hip_bf16.h>

#define NN 100000
#define EE 1600000
#define NB_SCAN 391   // ceil(NN/256)

// ---- bucketed CSR parameters ----
#define NBUCK 391     // dst>>8 -> 391 buckets of 256 nodes
#define CPAD  16      // cursor padding (64B)
#define NPART 391     // partition chunks (4096 edges each)
#define NE4   400000  // EE/4
#define CAP   8192    // fixed slots per bucket (mean 4093, sd ~64 -> 64 sigma)
#define CAPSH 13

typedef __hip_bfloat16 bf16_t;
typedef int int4v __attribute__((ext_vector_type(4)));
typedef float f4 __attribute__((ext_vector_type(4)));

// ---- workspace layout (float offsets); ws is 256 MiB ----
#define EMB   604480            // N*32 raw embeddings
#define PBUF  3804480           // N*32 P'
#define QBUF  7004480           // N*32 bf16 Q (uses half; keeps layout stable)
#define ABUF  10204480          // N*32 agg
#define SOFF  13404480          // ZERO REGION start: stats[0:128); [130] tcur; [131] ofl count
#define CURS  (SOFF + 256)      // NBUCK*CPAD ints (relative cursors, zero-init)
#define NZERO (256 + NBUCK * CPAD)   // floats to memset
#define ROWP2 (CURS + 12512)    // NN int2 (beg,end)
#define OFLB  (ROWP2 + 200000)  // int2 overflow entries
#define PEB   (OFLB + 3200004)  // NBUCK*CAP packed edges
#define SRCB  (PEB + 3203072)   // NBUCK*CAP + EE src lists (tail region for overflow)

// ---- raw param pointer indices (d_in[4+t]) ----
// 0 W_cont 1 b_cont 2 T_chrg 3 T_pdg 4 T_pv 5 W_cat 6 b_cat 7 W_enc 8 b_enc
// 9 g_all 10 be_all 11 W_msg 12 b_msg 13 g_conv 14 be_conv
// 15 W_out1 16 b_out1 17 W_out2 18 b_out2
struct P19 { const void* p[19]; };

__device__ __forceinline__ float bf(unsigned short u) {
    return __uint_as_float(((unsigned)u) << 16);
}
__device__ __forceinline__ float ldp(const void* p, int i, int f32) {
    return f32 ? ((const float*)p)[i] : bf(((const unsigned short*)p)[i]);
}
__device__ __forceinline__ unsigned short f2b(float f) {
    __hip_bfloat16 h = __float2bfloat16(f);          // round-to-nearest-even
    return *reinterpret_cast<unsigned short*>(&h);
}
__device__ __forceinline__ f4 elu4(f4 v) {
    f4 r;
    r.x = v.x > 0.0f ? v.x : expm1f(v.x);
    r.y = v.y > 0.0f ? v.y : expm1f(v.y);
    r.z = v.z > 0.0f ? v.z : expm1f(v.z);
    r.w = v.w > 0.0f ? v.w : expm1f(v.w);
    return r;
}
__device__ __forceinline__ f4 f4max(f4 a, f4 b) {
    f4 r;
    r.x = fmaxf(a.x, b.x); r.y = fmaxf(a.y, b.y);
    r.z = fmaxf(a.z, b.z); r.w = fmaxf(a.w, b.w);
    return r;
}
__device__ __forceinline__ f4 unpack_q(uint2 q) {
    f4 r;
    r.x = __uint_as_float(q.x << 16);
    r.y = __uint_as_float(q.x & 0xFFFF0000u);
    r.z = __uint_as_float(q.y << 16);
    r.w = __uint_as_float(q.y & 0xFFFF0000u);
    return r;
}
// wave-64 inclusive scan
__device__ __forceinline__ int wave_iscan(int x, int lane) {
    #pragma unroll
    for (int off = 1; off < 64; off <<= 1) {
        int y = __shfl_up(x, off);
        if (lane >= off) x += y;
    }
    return x;
}
// per-block dtype sniff of W_enc raw halves (1024 elems); |v|>=2^10 as bf16 -> f32 data
__device__ __forceinline__ int detect_f32(const unsigned short* w, int tid, int* sh)
{
    if (tid == 0) *sh = 0;
    __syncthreads();
    int bad = 0;
    for (int i = tid; i < 1024; i += 256) {
        unsigned e = (w[i] >> 7) & 0xFFu;
        if (e >= 137u) bad = 1;
    }
    unsigned long long m = __ballot(bad);
    if ((tid & 63) == 0 && m != 0ull) atomicOr(sh, 1);
    __syncthreads();
    return *sh;
}

// ---------------- fused A: partition w/ counting-sort (0..390) | embed+stats1 (391..781) ----------------
struct SMemPart {
    int cnt[NBUCK];
    int lstart[NBUCK];
    int gstart[NBUCK];
    int wsum[4];
    unsigned short bkof[4096];
    int staged[4096];
};
struct SMemEmb  { float wc[96], bc[16], tc[24], tp[56], tv[64],
                  wcat[384], bcat[16], we[1024], be[32], ls[64]; };
union SMemA { SMemPart p; SMemEmb e; };

__global__ __launch_bounds__(256, 1) void k_fA(
    const int* __restrict__ eidx, int* __restrict__ curs,
    int* __restrict__ pe, int* __restrict__ oflc, int2* __restrict__ ofl2,
    const void* __restrict__ xc, const int* __restrict__ x_cat,
    P19 pp, float* __restrict__ emb, float* __restrict__ stats)
{
    __shared__ alignas(16) SMemA sm;
    __shared__ int sdet;
    int tid = threadIdx.x;
    int b = blockIdx.x;
    int lane = tid & 63;
    int wid = tid >> 6;

    if (b < NPART) {
        // ---- phase 1: load dst ONCE into registers + count ----
        for (int i = tid; i < NBUCK; i += 256) sm.p.cnt[i] = 0;
        __syncthreads();
        const int4v* src4 = (const int4v*)eidx;
        const int4v* dst4 = (const int4v*)(eidx + EE);
        int i0 = b << 10;
        int i1 = i0 + 1024; if (i1 > NE4) i1 = NE4;
        int nE = (i1 - i0) * 4;
        int4v dreg[4];
        #pragma unroll
        for (int k = 0; k < 4; k++) {
            int i = i0 + k * 256 + tid;
            if (i < i1) {
                int4v d = __builtin_nontemporal_load(&dst4[i]);
                dreg[k] = d;
                atomicAdd(&sm.p.cnt[d.x >> 8], 1);
                atomicAdd(&sm.p.cnt[d.y >> 8], 1);
                atomicAdd(&sm.p.cnt[d.z >> 8], 1);
                atomicAdd(&sm.p.cnt[d.w >> 8], 1);
            }
        }
        __syncthreads();
        // ---- phase 2: wave-shuffle scan (thread t owns [4t,4t+4)) + global reserve ----
        int base = tid * 4;
        int c0 = (base     < NBUCK) ? sm.p.cnt[base    ] : 0;
        int c1 = (base + 1 < NBUCK) ? sm.p.cnt[base + 1] : 0;
        int c2 = (base + 2 < NBUCK) ? sm.p.cnt[base + 2] : 0;
        int c3 = (base + 3 < NBUCK) ? sm.p.cnt[base + 3] : 0;
        int s = c0 + c1 + c2 + c3;
        int inc = wave_iscan(s, lane);
        if (lane == 63) sm.p.wsum[wid] = inc;
        __syncthreads();
        int run = inc - s;
        #pragma unroll
        for (int w = 0; w < 4; w++) if (w < wid) run += sm.p.wsum[w];
        // cursors are RELATIVE (zero-init via memset); store absolute starts in LDS
        if (base < NBUCK) {
            sm.p.lstart[base] = run;
            if (c0) sm.p.gstart[base] = (base << CAPSH) + atomicAdd(&curs[base * CPAD], c0);
            run += c0;
        }
        if (base + 1 < NBUCK) {
            sm.p.lstart[base + 1] = run;
            if (c1) sm.p.gstart[base + 1] = ((base + 1) << CAPSH) + atomicAdd(&curs[(base + 1) * CPAD], c1);
            run += c1;
        }
        if (base + 2 < NBUCK) {
            sm.p.lstart[base + 2] = run;
            if (c2) sm.p.gstart[base + 2] = ((base + 2) << CAPSH) + atomicAdd(&curs[(base + 2) * CPAD], c2);
            run += c2;
        }
        if (base + 3 < NBUCK) {
            sm.p.lstart[base + 3] = run;
            if (c3) sm.p.gstart[base + 3] = ((base + 3) << CAPSH) + atomicAdd(&curs[(base + 3) * CPAD], c3);
            run += c3;
        }
        __syncthreads();
        // ---- phase 3: bucket-of-position map + inline cnt reset ----
        for (int i = tid; i < NBUCK; i += 256) {
            int st = sm.p.lstart[i], c = sm.p.cnt[i];
            for (int j = 0; j < c; j++) sm.p.bkof[st + j] = (unsigned short)i;
            sm.p.cnt[i] = 0;
        }
        __syncthreads();
        // ---- phase 4: place into bucket-ordered LDS staging (dst from regs) ----
        #pragma unroll
        for (int k = 0; k < 4; k++) {
            int i = i0 + k * 256 + tid;
            if (i < i1) {
                int4v s4 = __builtin_nontemporal_load(&src4[i]);
                int4v d4 = dreg[k];
                #define PLACE(SS, DD) { \
                    int bk = (DD) >> 8; \
                    int r = atomicAdd(&sm.p.cnt[bk], 1); \
                    sm.p.staged[sm.p.lstart[bk] + r] = ((SS) << 8) | ((DD) & 255); }
                PLACE(s4.x, d4.x) PLACE(s4.y, d4.y) PLACE(s4.z, d4.z) PLACE(s4.w, d4.w)
                #undef PLACE
            }
        }
        __syncthreads();
        // ---- phase 5: coalesced flush ----
        for (int j = tid; j < nE; j += 256) {
            int bk = sm.p.bkof[j];
            int slot = sm.p.gstart[bk] + (j - sm.p.lstart[bk]);
            int packed = sm.p.staged[j];
            if (slot < ((bk + 1) << CAPSH)) pe[slot] = packed;
            else { int oi = atomicAdd(oflc, 1); ofl2[oi] = make_int2(bk, packed); }
        }
        return;
    }

    // ---- embed path + fused bn1 stats; params converted from raw inputs in-block ----
    int f32 = detect_f32((const unsigned short*)pp.p[7], tid, &sdet);
    {
        float* s;
        s=sm.e.wc;   for(int i=tid;i<96;  i+=256) s[i]=ldp(pp.p[0],i,f32);
        s=sm.e.bc;   for(int i=tid;i<16;  i+=256) s[i]=ldp(pp.p[1],i,f32);
        s=sm.e.tc;   for(int i=tid;i<24;  i+=256) s[i]=ldp(pp.p[2],i,f32);
        s=sm.e.tp;   for(int i=tid;i<56;  i+=256) s[i]=ldp(pp.p[3],i,f32);
        s=sm.e.tv;   for(int i=tid;i<64;  i+=256) s[i]=ldp(pp.p[4],i,f32);
        s=sm.e.wcat; for(int i=tid;i<384; i+=256) s[i]=ldp(pp.p[5],i,f32);
        s=sm.e.bcat; for(int i=tid;i<16;  i+=256) s[i]=ldp(pp.p[6],i,f32);
        s=sm.e.we;   for(int i=tid;i<1024;i+=256) s[i]=ldp(pp.p[7],i,f32);
        s=sm.e.be;   for(int i=tid;i<32;  i+=256) s[i]=ldp(pp.p[8],i,f32);
        if (tid < 64) sm.e.ls[tid] = 0.0f;
    }
    __syncthreads();

    int n = (b - NPART) * 256 + tid;
    // v[0:32) per-channel sums, v[32:64) per-channel sq
    float v[64];
    #pragma unroll
    for (int i = 0; i < 64; i++) v[i] = 0.0f;

    if (n < NN) {
        f4* sWc4 = (f4*)sm.e.wc;  f4* sbc4 = (f4*)sm.e.bc;
        f4* sTc4 = (f4*)sm.e.tc;  f4* sTp4 = (f4*)sm.e.tp;  f4* sTv4 = (f4*)sm.e.tv;
        f4* sWcat4 = (f4*)sm.e.wcat; f4* sbcat4 = (f4*)sm.e.bcat;
        f4* sWe4 = (f4*)sm.e.we;  f4* sbe4 = (f4*)sm.e.be;

        float x0,x1,x2,x3,x4,x5;
        if (f32) {
            const float* xr = (const float*)xc + (size_t)n * 6;
            x0=xr[0]; x1=xr[1]; x2=xr[2]; x3=xr[3]; x4=xr[4]; x5=xr[5];
        } else {
            const unsigned* xr = (const unsigned*)xc + (size_t)n * 3;
            unsigned w0=xr[0], w1=xr[1], w2=xr[2];
            x0=__uint_as_float(w0<<16); x1=__uint_as_float(w0 & 0xFFFF0000u);
            x2=__uint_as_float(w1<<16); x3=__uint_as_float(w1 & 0xFFFF0000u);
            x4=__uint_as_float(w2<<16); x5=__uint_as_float(w2 & 0xFFFF0000u);
        }

        f4 ec[4];
        #pragma unroll
        for (int g = 0; g < 4; g++) {
            f4 acc = sbc4[g];
            acc += x0 * sWc4[0*4+g]; acc += x1 * sWc4[1*4+g]; acc += x2 * sWc4[2*4+g];
            acc += x3 * sWc4[3*4+g]; acc += x4 * sWc4[4*4+g]; acc += x5 * sWc4[5*4+g];
            ec[g] = elu4(acc);
        }

        int c0 = x_cat[n*3+0], c1 = x_cat[n*3+1], c2 = x_cat[n*3+2];
        int a0 = c0 < 0 ? -c0 : c0;
        int pi = (a0==1)?0:(a0==2)?1:(a0==11)?2:(a0==13)?3:(a0==22)?4:(a0==130)?5:6;
        int ci = c1 + 1;

        f4 t0a = sTc4[ci*2],  t0b = sTc4[ci*2+1];
        f4 t1a = sTp4[pi*2],  t1b = sTp4[pi*2+1];
        f4 t2a = sTv4[c2*2],  t2b = sTv4[c2*2+1];

        f4 ecat[4];
        #pragma unroll
        for (int g = 0; g < 4; g++) {
            f4 acc = sbcat4[g];
            #pragma unroll
            for (int k = 0; k < 4; k++) acc += t0a[k] * sWcat4[(k     )*4+g];
            #pragma unroll
            for (int k = 0; k < 4; k++) acc += t0b[k] * sWcat4[(4 + k )*4+g];
            #pragma unroll
            for (int k = 0; k < 4; k++) acc += t1a[k] * sWcat4[(8 + k )*4+g];
            #pragma unroll
            for (int k = 0; k < 4; k++) acc += t1b[k] * sWcat4[(12 + k)*4+g];
            #pragma unroll
            for (int k = 0; k < 4; k++) acc += t2a[k] * sWcat4[(16 + k)*4+g];
            #pragma unroll
            for (int k = 0; k < 4; k++) acc += t2b[k] * sWcat4[(20 + k)*4+g];
            ecat[g] = elu4(acc);
        }

        f4* o = (f4*)(emb + (size_t)n * 32);
        #pragma unroll
        for (int cg = 0; cg < 8; cg++) {
            f4 acc = sbe4[cg];
            #pragma unroll
            for (int kg = 0; kg < 4; kg++) {
                #pragma unroll
                for (int k = 0; k < 4; k++)
                    acc += ecat[kg][k] * sWe4[(kg*4+k)*8 + cg];
            }
            #pragma unroll
            for (int kg = 0; kg < 4; kg++) {
                #pragma unroll
                for (int k = 0; k < 4; k++)
                    acc += ec[kg][k] * sWe4[(16 + kg*4+k)*8 + cg];
            }
            f4 val = elu4(acc);
            o[cg] = val;
            #pragma unroll
            for (int k = 0; k < 4; k++) {
                v[cg*4+k]      = val[k];
                v[32+cg*4+k]   = val[k] * val[k];
            }
        }
    }

    // multi-value fold reduce: 63 shuffles; lane ends owning index bitrev6(lane)
    #pragma unroll
    for (int st = 0; st < 6; st++) {
        int off = 1 << st;
        int keep = (lane >> st) & 1;
        int L2 = 32 >> st;
        #pragma unroll
        for (int i = 0; i < 32; i++) {
            if (i < L2) {
                float lo = v[i], hi = v[L2 + i];
                float sent = keep ? lo : hi;
                float got = __shfl_xor(sent, off);
                v[i] = (keep ? hi : lo) + got;
            }
        }
    }
    int idx = ((lane&1)<<5)|((lane&2)<<3)|((lane&4)<<1)|((lane&8)>>1)|((lane&16)>>3)|((lane&32)>>5);
    atomicAdd(&sm.e.ls[idx], v[0]);
    __syncthreads();
    if (tid < 64) atomicAdd(&stats[tid], sm.e.ls[tid]);
}

// ---------------- fused B: per-bucket CSR (0..390) | P,Q build (391..781) ----------------
struct SMemCsr { int cnt[256]; int ex[256]; int wsum[4]; int tl; };
struct SMemPq  { float wp[1024], wq[1024], bp[32], bq[32], ssc[32], ssh[32]; };
union SMemB { SMemCsr c; SMemPq q; };

__global__ __launch_bounds__(256) void k_fB(
    const int* __restrict__ curs, const int* __restrict__ pe,
    const int* __restrict__ oflc, const int2* __restrict__ ofl2,
    int* __restrict__ tcur, int2* __restrict__ rowp2, int* __restrict__ srcl,
    const float* __restrict__ emb, const float* __restrict__ stats,
    P19 pp, float* __restrict__ P, unsigned short* __restrict__ Qh)
{
    __shared__ alignas(16) SMemB sm;
    __shared__ int sdet;
    int tid = threadIdx.x;
    int b = blockIdx.x;
    int lane = tid & 63;
    int wid = tid >> 6;

    if (b < NBUCK) {
        int beg = b << CAPSH;
        int m_res = curs[b * CPAD];                  // relative cursor == bucket edge count
        int stored = m_res < CAP ? m_res : CAP;
        int no = oflc[0];                             // overflow entries (normally 0)
        sm.c.cnt[tid] = 0;
        __syncthreads();
        // count pass (pe region is L1/L2-resident for the re-read below)
        for (int i = tid; i < stored; i += 256) {
            int p = pe[beg + i];
            atomicAdd(&sm.c.cnt[p & 255], 1);
        }
        for (int j = tid; j < no; j += 256) {
            int2 oe = ofl2[j];
            if (oe.x == b) atomicAdd(&sm.c.cnt[oe.y & 255], 1);
        }
        __syncthreads();
        // wave-shuffle scan over the 256 per-node counts
        int deg = sm.c.cnt[tid];
        int inc = wave_iscan(deg, lane);
        if (lane == 63) sm.c.wsum[wid] = inc;
        __syncthreads();
        int e0 = inc - deg;
        #pragma unroll
        for (int w = 0; w < 4; w++) if (w < wid) e0 += sm.c.wsum[w];
        int obeg = beg;
        if (m_res > CAP) {                            // astronomically rare: tail-allocate
            if (tid == 0) sm.c.tl = (NBUCK << CAPSH) + atomicAdd(tcur, m_res);
            __syncthreads();
            obeg = sm.c.tl;
        }
        sm.c.ex[tid] = e0;
        int node = b * 256 + tid;
        if (node < NN) rowp2[node] = make_int2(obeg + e0, obeg + e0 + deg);
        sm.c.cnt[tid] = 0;
        __syncthreads();
        // place pass
        for (int i = tid; i < stored; i += 256) {
            int p = pe[beg + i];
            int dl = p & 255;
            int r = atomicAdd(&sm.c.cnt[dl], 1);
            srcl[obeg + sm.c.ex[dl] + r] = p >> 8;
        }
        for (int j = tid; j < no; j += 256) {
            int2 oe = ofl2[j];
            if (oe.x == b) {
                int dl = oe.y & 255;
                int r = atomicAdd(&sm.c.cnt[dl], 1);
                srcl[obeg + sm.c.ex[dl] + r] = oe.y >> 8;
            }
        }
        return;
    }

    // ---- P,Q build (bn1 + Wmsg folded); params converted from raw; Q written as bf16 ----
    int f32 = detect_f32((const unsigned short*)pp.p[7], tid, &sdet);
    if (tid < 32) {
        float mu  = stats[tid] * (1.0f / NN);
        float var = stats[32 + tid] * (1.0f / NN) - mu * mu;
        float s   = ldp(pp.p[9], tid, f32) * rsqrtf(var + 1e-5f);
        sm.q.ssc[tid] = s;
        sm.q.ssh[tid] = ldp(pp.p[10], tid, f32) - mu * s;
    }
    __syncthreads();
    for (int e = tid; e < 1024; e += 256) {
        int k = e >> 5;
        float w1 = ldp(pp.p[11], e, f32);
        float w2 = ldp(pp.p[11], 1024 + e, f32);
        sm.q.wp[e] = sm.q.ssc[k] * (w1 - w2);
        sm.q.wq[e] = sm.q.ssc[k] * w2;
    }
    if (tid < 32) {
        float aP = ldp(pp.p[12], tid, f32), aQ = 0.0f;
        for (int k = 0; k < 32; k++) {
            float w1 = ldp(pp.p[11], k*32 + tid, f32);
            float w2 = ldp(pp.p[11], (k+32)*32 + tid, f32);
            aP += sm.q.ssh[k] * (w1 - w2);
            aQ += sm.q.ssh[k] * w2;
        }
        sm.q.bp[tid] = aP;
        sm.q.bq[tid] = aQ;
    }
    __syncthreads();

    int n = (b - NBUCK) * 256 + tid;
    if (n >= NN) return;

    f4* sWP4 = (f4*)sm.q.wp; f4* sWQ4 = (f4*)sm.q.wq;
    f4* sbP4 = (f4*)sm.q.bp; f4* sbQ4 = (f4*)sm.q.bq;
    const f4* er = (const f4*)(emb + (size_t)n * 32);
    f4 e[8];
    #pragma unroll
    for (int g = 0; g < 8; g++) e[g] = er[g];
    f4* pr = (f4*)(P + (size_t)n * 32);
    uint2* qr = (uint2*)(Qh + (size_t)n * 32);
    #pragma unroll
    for (int cg = 0; cg < 8; cg++) {
        f4 aP = sbP4[cg];
        f4 aQ = sbQ4[cg];
        #pragma unroll
        for (int kg = 0; kg < 8; kg++) {
            #pragma unroll
            for (int k = 0; k < 4; k++) {
                float ek = e[kg][k];
                aP += ek * sWP4[(kg*4+k)*8 + cg];
                aQ += ek * sWQ4[(kg*4+k)*8 + cg];
            }
        }
        pr[cg] = aP;
        uint2 qp;
        qp.x = (unsigned)f2b(aQ.x) | ((unsigned)f2b(aQ.y) << 16);
        qp.y = (unsigned)f2b(aQ.z) | ((unsigned)f2b(aQ.w) << 16);
        qr[cg] = qp;
    }
}

// ---------------- gather-max: 2 nodes per wave; bf16 Q rows (64 B/node) ----------------
__global__ __launch_bounds__(256) void k_gather(
    const int2* __restrict__ rowp2, const int* __restrict__ srcl,
    const unsigned short* __restrict__ Qh, const float* __restrict__ P,
    float* __restrict__ agg)
{
    int tid = threadIdx.x;
    int lane = tid & 63;
    int wave = tid >> 6;
    int half  = lane >> 5;               // which node of the pair
    int hl    = lane & 31;
    int slice = hl >> 3;                 // 0..3 edge slice
    int cg    = hl & 7;                  // channel group
    int n = (blockIdx.x * 4 + wave) * 2 + half;   // 12500 blocks x 4 waves x 2 nodes
    int2 be = rowp2[n];
    int beg = be.x, end = be.y;
    const uint2* Q2 = (const uint2*)Qh;  // 8 uint2 per node row

    // hoisted P read (independent of the edge loop)
    f4 pv = (f4){0.f, 0.f, 0.f, 0.f};
    if (hl < 8 && end > beg) pv = ((const f4*)P)[(size_t)n * 8 + hl];

    f4 m = {-INFINITY, -INFINITY, -INFINITY, -INFINITY};
    // 4 edge-slots per lane per iteration; clamped dup indices are harmless under max
    for (int e = beg + slice; e < end; e += 16) {
        int e1 = min(e + 4,  end - 1);
        int e2 = min(e + 8,  end - 1);
        int e3 = min(e + 12, end - 1);
        int s0 = __builtin_nontemporal_load(&srcl[e]);
        int s1 = __builtin_nontemporal_load(&srcl[e1]);
        int s2 = __builtin_nontemporal_load(&srcl[e2]);
        int s3 = __builtin_nontemporal_load(&srcl[e3]);
        f4 q0 = unpack_q(Q2[(size_t)s0 * 8 + cg]);
        f4 q1 = unpack_q(Q2[(size_t)s1 * 8 + cg]);
        f4 q2 = unpack_q(Q2[(size_t)s2 * 8 + cg]);
        f4 q3 = unpack_q(Q2[(size_t)s3 * 8 + cg]);
        q0 = f4max(q0, q1);
        q2 = f4max(q2, q3);
        m = f4max(m, f4max(q0, q2));
    }
    // reduce across the 4 slices of each half-wave (xor 8, 16 stay within the half)
    #pragma unroll
    for (int off = 8; off < 32; off <<= 1) {
        m.x = fmaxf(m.x, __shfl_xor(m.x, off));
        m.y = fmaxf(m.y, __shfl_xor(m.y, off));
        m.z = fmaxf(m.z, __shfl_xor(m.z, off));
        m.w = fmaxf(m.w, __shfl_xor(m.w, off));
    }
    if (hl < 8) {
        f4 o;
        if (end > beg) o = m + pv;
        else           o = (f4){0.f, 0.f, 0.f, 0.f};
        ((f4*)agg)[(size_t)n * 8 + hl] = o;
    }
}

// ---------------- stats2: per-channel sum & sumsq over agg ----------------
__global__ __launch_bounds__(256) void k_stats(const float* __restrict__ xin,
                                               float* __restrict__ outsums, int count)
{
    __shared__ float ls[64];
    int tid = threadIdx.x;
    if (tid < 64) ls[tid] = 0.0f;
    __syncthreads();
    int idx = blockIdx.x * 256 + tid;
    int stride = gridDim.x * 256;
    int c = idx & 31;
    float s = 0.0f, q = 0.0f;
    for (int i = idx; i < count; i += stride) {
        float v = xin[i];
        s += v; q += v * v;
    }
    s += __shfl_xor(s, 32);
    q += __shfl_xor(q, 32);
    if ((tid & 63) < 32) {
        atomicAdd(&ls[c], s);
        atomicAdd(&ls[32 + c], q);
    }
    __syncthreads();
    if (tid < 64) atomicAdd(&outsums[tid], ls[tid]);
}

// ---------------- output MLP: 8 lanes per node, shuffle-reduced (32 nodes/block) ----------------
__global__ __launch_bounds__(256, 1) void k_out(
    const float* __restrict__ emb, const float* __restrict__ agg,
    P19 pp, const float* __restrict__ stats, void* __restrict__ out)
{
    __shared__ f4 sW14[128];    // [32][16] as f4: row k, out-group g -> sW14[k*4+g]
    __shared__ f4 sb14[4], sW24[4];
    __shared__ f4 sc14[8], sh14[8], sc24[8], sh24[8];
    __shared__ float sb2s;
    __shared__ int sdet;
    int tid = threadIdx.x;
    int f32 = detect_f32((const unsigned short*)pp.p[7], tid, &sdet);
    {
        float* s = (float*)sW14;
        for (int i = tid; i < 512; i += 256) s[i] = ldp(pp.p[15], i, f32);
    }
    if (tid < 16) {
        ((float*)sb14)[tid] = ldp(pp.p[16], tid, f32);
        ((float*)sW24)[tid] = ldp(pp.p[17], tid, f32);
    }
    if (tid < 32) {
        float mu  = stats[tid] * (1.0f / NN);
        float var = stats[32 + tid] * (1.0f / NN) - mu * mu;
        float s   = ldp(pp.p[9], tid, f32) * rsqrtf(var + 1e-5f);
        ((float*)sc14)[tid] = s;
        ((float*)sh14)[tid] = ldp(pp.p[10], tid, f32) - mu * s;
        float mu2  = stats[64 + tid] * (1.0f / NN);
        float var2 = stats[96 + tid] * (1.0f / NN) - mu2 * mu2;
        float s2   = ldp(pp.p[13], tid, f32) * rsqrtf(var2 + 1e-5f);
        ((float*)sc24)[tid] = s2;
        ((float*)sh24)[tid] = ldp(pp.p[14], tid, f32) - mu2 * s2;
    }
    if (tid == 0) sb2s = ldp(pp.p[18], 0, f32);
    __syncthreads();

    int grp = tid >> 3;                  // node index within block (0..31)
    int l   = tid & 7;                   // lane within node-group; owns channels [4l,4l+4)
    int n = blockIdx.x * 32 + grp;
    if (n >= NN) return;

    // this lane's 4 channels of the bn-normalized hidden vector
    f4 ev = ((const f4*)(emb + (size_t)n * 32))[l];
    f4 av = ((const f4*)(agg + (size_t)n * 32))[l];
    f4 h4 = ev * sc14[l] + sh14[l] + av * sc24[l] + sh24[l];

    // partial products for all 16 outputs from this lane's 4 input rows
    f4 o1[4];
    #pragma unroll
    for (int g = 0; g < 4; g++) o1[g] = (f4){0.f, 0.f, 0.f, 0.f};
    #pragma unroll
    for (int kk = 0; kk < 4; kk++) {
        int k = l * 4 + kk;
        float hv = h4[kk];
        #pragma unroll
        for (int g = 0; g < 4; g++) o1[g] += hv * sW14[k * 4 + g];
    }
    // reduce across the 8 lanes of this node-group (xor 1,2,4 stays in-group)
    #pragma unroll
    for (int off = 1; off < 8; off <<= 1) {
        #pragma unroll
        for (int g = 0; g < 4; g++) {
            o1[g].x += __shfl_xor(o1[g].x, off);
            o1[g].y += __shfl_xor(o1[g].y, off);
            o1[g].z += __shfl_xor(o1[g].z, off);
            o1[g].w += __shfl_xor(o1[g].w, off);
        }
    }
    if (l == 0) {
        float acc = sb2s;
        #pragma unroll
        for (int g = 0; g < 4; g++) {
            f4 p = elu4(o1[g] + sb14[g]) * sW24[g];
            acc += p.x + p.y + p.z + p.w;
        }
        if (f32) ((float*)out)[n] = acc;
        else     ((bf16_t*)out)[n] = __float2bfloat16(acc);
    }
}

// ======================= launcher (5 dispatches + 1 memset) =======================

extern "C" void kernel_launch(void* const* d_in, const int* in_sizes, int n_in,
                              void* d_out, int out_size, void* d_ws, size_t ws_size,
                              hipStream_t stream)
{
    const void* x_cont = d_in[0];
    const int* x_cat = (const int*)d_in[1];
    const int* eidx  = (const int*)d_in[2];

    float* ws    = (float*)d_ws;
    float* emb   = ws + EMB;
    float* P     = ws + PBUF;
    unsigned short* Qh = (unsigned short*)(ws + QBUF);
    float* agg   = ws + ABUF;
    float* stats = ws + SOFF;
    int*   tcur  = (int*)(stats + 130);
    int*   oflc  = (int*)(stats + 131);
    int*   curs  = (int*)(ws + CURS);
    int2*  rowp2 = (int2*)(ws + ROWP2);
    int2*  ofl2  = (int2*)(ws + OFLB);
    int*   pe    = (int*)(ws + PEB);
    int*   srcl  = (int*)(ws + SRCB);

    P19 pp;
    for (int t = 0; t < 19; t++) pp.p[t] = d_in[4 + t];

    // zero the whole control region: stats(128) + scratch(128) + relative cursors
    hipMemsetAsync(ws + SOFF, 0, (size_t)NZERO * sizeof(float), stream);

    k_fA<<<NPART + NB_SCAN, 256, 0, stream>>>(eidx, curs, pe, oflc, ofl2,
                                              x_cont, x_cat, pp, emb, stats);
    k_fB<<<NBUCK + NB_SCAN, 256, 0, stream>>>(curs, pe, oflc, ofl2, tcur, rowp2, srcl,
                                              emb, stats, pp, P, Qh);
    k_gather<<<NN / 8, 256, 0, stream>>>(rowp2, srcl, Qh, P, agg);
    k_stats<<<512, 256, 0, stream>>>(agg, stats + 64, NN * 32);
    k_out<<<(NN + 31) / 32, 256, 0, stream>>>(emb, agg, pp, stats, d_out);
}

// Round 15
// 236.838 us; speedup vs baseline: 1.0505x; 1.0505x over previous
//
#include <hip/hip_runtime.h>
#include <hip/hip_bf16.h>

#define NN 100000
#define EE 1600000
#define NB_SCAN 391   // ceil(NN/256)

// ---- bucketed CSR parameters ----
#define NBUCK 391     // dst>>8 -> 391 buckets of 256 nodes
#define CPAD  16      // cursor padding (64B)
#define NPART 391     // partition chunks (4096 edges each)
#define NE4   400000  // EE/4
#define CAP   8192    // fixed slots per bucket (mean 4093, sd ~64 -> 64 sigma)
#define CAPSH 13

typedef __hip_bfloat16 bf16_t;
typedef int int4v __attribute__((ext_vector_type(4)));
typedef float f4 __attribute__((ext_vector_type(4)));

// ---- workspace layout (float offsets); ws is 256 MiB ----
#define EMB   604480            // N*32 raw embeddings
#define PBUF  3804480           // N*32 P'
#define QBUF  7004480           // N*32 bf16 Q (uses half; keeps layout stable)
#define ABUF  10204480          // N*32 agg
#define SOFF  13404480          // ZERO REGION start: stats[0:128); [130] tcur; [131] ofl count
#define CURS  (SOFF + 256)      // NBUCK*CPAD ints (relative cursors, zero-init)
#define NZERO (256 + NBUCK * CPAD)   // floats to memset
#define ROWP2 (CURS + 12512)    // NN int2 (beg,end)
#define OFLB  (ROWP2 + 200000)  // int2 overflow entries
#define PEB   (OFLB + 3200004)  // NBUCK*CAP packed edges
#define SRCB  (PEB + 3203072)   // NBUCK*CAP + EE src lists (tail region for overflow)

// ---- raw param pointer indices (d_in[4+t]) ----
// 0 W_cont 1 b_cont 2 T_chrg 3 T_pdg 4 T_pv 5 W_cat 6 b_cat 7 W_enc 8 b_enc
// 9 g_all 10 be_all 11 W_msg 12 b_msg 13 g_conv 14 be_conv
// 15 W_out1 16 b_out1 17 W_out2 18 b_out2
struct P19 { const void* p[19]; };

__device__ __forceinline__ float bf(unsigned short u) {
    return __uint_as_float(((unsigned)u) << 16);
}
__device__ __forceinline__ float ldp(const void* p, int i, int f32) {
    return f32 ? ((const float*)p)[i] : bf(((const unsigned short*)p)[i]);
}
__device__ __forceinline__ unsigned short f2b(float f) {
    __hip_bfloat16 h = __float2bfloat16(f);          // round-to-nearest-even
    return *reinterpret_cast<unsigned short*>(&h);
}
__device__ __forceinline__ f4 elu4(f4 v) {
    f4 r;
    r.x = v.x > 0.0f ? v.x : expm1f(v.x);
    r.y = v.y > 0.0f ? v.y : expm1f(v.y);
    r.z = v.z > 0.0f ? v.z : expm1f(v.z);
    r.w = v.w > 0.0f ? v.w : expm1f(v.w);
    return r;
}
__device__ __forceinline__ f4 f4max(f4 a, f4 b) {
    f4 r;
    r.x = fmaxf(a.x, b.x); r.y = fmaxf(a.y, b.y);
    r.z = fmaxf(a.z, b.z); r.w = fmaxf(a.w, b.w);
    return r;
}
__device__ __forceinline__ f4 unpack_q(uint2 q) {
    f4 r;
    r.x = __uint_as_float(q.x << 16);
    r.y = __uint_as_float(q.x & 0xFFFF0000u);
    r.z = __uint_as_float(q.y << 16);
    r.w = __uint_as_float(q.y & 0xFFFF0000u);
    return r;
}
// wave-64 inclusive scan
__device__ __forceinline__ int wave_iscan(int x, int lane) {
    #pragma unroll
    for (int off = 1; off < 64; off <<= 1) {
        int y = __shfl_up(x, off);
        if (lane >= off) x += y;
    }
    return x;
}
// per-block dtype sniff of W_enc raw halves (1024 elems); |v|>=2^10 as bf16 -> f32 data
__device__ __forceinline__ int detect_f32(const unsigned short* w, int tid, int* sh)
{
    if (tid == 0) *sh = 0;
    __syncthreads();
    int bad = 0;
    for (int i = tid; i < 1024; i += 256) {
        unsigned e = (w[i] >> 7) & 0xFFu;
        if (e >= 137u) bad = 1;
    }
    unsigned long long m = __ballot(bad);
    if ((tid & 63) == 0 && m != 0ull) atomicOr(sh, 1);
    __syncthreads();
    return *sh;
}

// ---------------- fused A: partition w/ counting-sort (0..390) | embed+stats1 (391..781) ----------------
struct SMemPart {
    int cnt[NBUCK];
    int lstart[NBUCK];
    int gstart[NBUCK];
    int wsum[4];
    unsigned short bkof[4096];
    int staged[4096];
};
struct SMemEmb  { float wc[96], bc[16], tc[24], tp[56], tv[64],
                  wcat[384], bcat[16], we[1024], be[32], ls[64]; };
union SMemA { SMemPart p; SMemEmb e; };

__global__ __launch_bounds__(256, 1) void k_fA(
    const int* __restrict__ eidx, int* __restrict__ curs,
    int* __restrict__ pe, int* __restrict__ oflc, int2* __restrict__ ofl2,
    const void* __restrict__ xc, const int* __restrict__ x_cat,
    P19 pp, float* __restrict__ emb, float* __restrict__ stats)
{
    __shared__ alignas(16) SMemA sm;
    __shared__ int sdet;
    int tid = threadIdx.x;
    int b = blockIdx.x;
    int lane = tid & 63;
    int wid = tid >> 6;

    if (b < NPART) {
        // ---- phase 1: load dst ONCE into registers + count ----
        for (int i = tid; i < NBUCK; i += 256) sm.p.cnt[i] = 0;
        __syncthreads();
        const int4v* src4 = (const int4v*)eidx;
        const int4v* dst4 = (const int4v*)(eidx + EE);
        int i0 = b << 10;
        int i1 = i0 + 1024; if (i1 > NE4) i1 = NE4;
        int nE = (i1 - i0) * 4;
        int4v dreg[4];
        #pragma unroll
        for (int k = 0; k < 4; k++) {
            int i = i0 + k * 256 + tid;
            if (i < i1) {
                int4v d = __builtin_nontemporal_load(&dst4[i]);
                dreg[k] = d;
                atomicAdd(&sm.p.cnt[d.x >> 8], 1);
                atomicAdd(&sm.p.cnt[d.y >> 8], 1);
                atomicAdd(&sm.p.cnt[d.z >> 8], 1);
                atomicAdd(&sm.p.cnt[d.w >> 8], 1);
            }
        }
        __syncthreads();
        // ---- phase 2: wave-shuffle scan (thread t owns [4t,4t+4)) + global reserve ----
        int base = tid * 4;
        int c0 = (base     < NBUCK) ? sm.p.cnt[base    ] : 0;
        int c1 = (base + 1 < NBUCK) ? sm.p.cnt[base + 1] : 0;
        int c2 = (base + 2 < NBUCK) ? sm.p.cnt[base + 2] : 0;
        int c3 = (base + 3 < NBUCK) ? sm.p.cnt[base + 3] : 0;
        int s = c0 + c1 + c2 + c3;
        int inc = wave_iscan(s, lane);
        if (lane == 63) sm.p.wsum[wid] = inc;
        __syncthreads();
        int run = inc - s;
        #pragma unroll
        for (int w = 0; w < 4; w++) if (w < wid) run += sm.p.wsum[w];
        // cursors are RELATIVE (zero-init via memset); store absolute starts in LDS
        if (base < NBUCK) {
            sm.p.lstart[base] = run;
            if (c0) sm.p.gstart[base] = (base << CAPSH) + atomicAdd(&curs[base * CPAD], c0);
            run += c0;
        }
        if (base + 1 < NBUCK) {
            sm.p.lstart[base + 1] = run;
            if (c1) sm.p.gstart[base + 1] = ((base + 1) << CAPSH) + atomicAdd(&curs[(base + 1) * CPAD], c1);
            run += c1;
        }
        if (base + 2 < NBUCK) {
            sm.p.lstart[base + 2] = run;
            if (c2) sm.p.gstart[base + 2] = ((base + 2) << CAPSH) + atomicAdd(&curs[(base + 2) * CPAD], c2);
            run += c2;
        }
        if (base + 3 < NBUCK) {
            sm.p.lstart[base + 3] = run;
            if (c3) sm.p.gstart[base + 3] = ((base + 3) << CAPSH) + atomicAdd(&curs[(base + 3) * CPAD], c3);
            run += c3;
        }
        __syncthreads();
        // ---- phase 3: bucket-of-position map + inline cnt reset ----
        for (int i = tid; i < NBUCK; i += 256) {
            int st = sm.p.lstart[i], c = sm.p.cnt[i];
            for (int j = 0; j < c; j++) sm.p.bkof[st + j] = (unsigned short)i;
            sm.p.cnt[i] = 0;
        }
        __syncthreads();
        // ---- phase 4: place into bucket-ordered LDS staging (dst from regs) ----
        #pragma unroll
        for (int k = 0; k < 4; k++) {
            int i = i0 + k * 256 + tid;
            if (i < i1) {
                int4v s4 = __builtin_nontemporal_load(&src4[i]);
                int4v d4 = dreg[k];
                #define PLACE(SS, DD) { \
                    int bk = (DD) >> 8; \
                    int r = atomicAdd(&sm.p.cnt[bk], 1); \
                    sm.p.staged[sm.p.lstart[bk] + r] = ((SS) << 8) | ((DD) & 255); }
                PLACE(s4.x, d4.x) PLACE(s4.y, d4.y) PLACE(s4.z, d4.z) PLACE(s4.w, d4.w)
                #undef PLACE
            }
        }
        __syncthreads();
        // ---- phase 5: coalesced flush ----
        for (int j = tid; j < nE; j += 256) {
            int bk = sm.p.bkof[j];
            int slot = sm.p.gstart[bk] + (j - sm.p.lstart[bk]);
            int packed = sm.p.staged[j];
            if (slot < ((bk + 1) << CAPSH)) pe[slot] = packed;
            else { int oi = atomicAdd(oflc, 1); ofl2[oi] = make_int2(bk, packed); }
        }
        return;
    }

    // ---- embed path + fused bn1 stats; params converted from raw inputs in-block ----
    int f32 = detect_f32((const unsigned short*)pp.p[7], tid, &sdet);
    {
        float* s;
        s=sm.e.wc;   for(int i=tid;i<96;  i+=256) s[i]=ldp(pp.p[0],i,f32);
        s=sm.e.bc;   for(int i=tid;i<16;  i+=256) s[i]=ldp(pp.p[1],i,f32);
        s=sm.e.tc;   for(int i=tid;i<24;  i+=256) s[i]=ldp(pp.p[2],i,f32);
        s=sm.e.tp;   for(int i=tid;i<56;  i+=256) s[i]=ldp(pp.p[3],i,f32);
        s=sm.e.tv;   for(int i=tid;i<64;  i+=256) s[i]=ldp(pp.p[4],i,f32);
        s=sm.e.wcat; for(int i=tid;i<384; i+=256) s[i]=ldp(pp.p[5],i,f32);
        s=sm.e.bcat; for(int i=tid;i<16;  i+=256) s[i]=ldp(pp.p[6],i,f32);
        s=sm.e.we;   for(int i=tid;i<1024;i+=256) s[i]=ldp(pp.p[7],i,f32);
        s=sm.e.be;   for(int i=tid;i<32;  i+=256) s[i]=ldp(pp.p[8],i,f32);
        if (tid < 64) sm.e.ls[tid] = 0.0f;
    }
    __syncthreads();

    int n = (b - NPART) * 256 + tid;
    // v[0:32) per-channel sums, v[32:64) per-channel sq
    float v[64];
    #pragma unroll
    for (int i = 0; i < 64; i++) v[i] = 0.0f;

    if (n < NN) {
        f4* sWc4 = (f4*)sm.e.wc;  f4* sbc4 = (f4*)sm.e.bc;
        f4* sTc4 = (f4*)sm.e.tc;  f4* sTp4 = (f4*)sm.e.tp;  f4* sTv4 = (f4*)sm.e.tv;
        f4* sWcat4 = (f4*)sm.e.wcat; f4* sbcat4 = (f4*)sm.e.bcat;
        f4* sWe4 = (f4*)sm.e.we;  f4* sbe4 = (f4*)sm.e.be;

        float x0,x1,x2,x3,x4,x5;
        if (f32) {
            const float* xr = (const float*)xc + (size_t)n * 6;
            x0=xr[0]; x1=xr[1]; x2=xr[2]; x3=xr[3]; x4=xr[4]; x5=xr[5];
        } else {
            const unsigned* xr = (const unsigned*)xc + (size_t)n * 3;
            unsigned w0=xr[0], w1=xr[1], w2=xr[2];
            x0=__uint_as_float(w0<<16); x1=__uint_as_float(w0 & 0xFFFF0000u);
            x2=__uint_as_float(w1<<16); x3=__uint_as_float(w1 & 0xFFFF0000u);
            x4=__uint_as_float(w2<<16); x5=__uint_as_float(w2 & 0xFFFF0000u);
        }

        f4 ec[4];
        #pragma unroll
        for (int g = 0; g < 4; g++) {
            f4 acc = sbc4[g];
            acc += x0 * sWc4[0*4+g]; acc += x1 * sWc4[1*4+g]; acc += x2 * sWc4[2*4+g];
            acc += x3 * sWc4[3*4+g]; acc += x4 * sWc4[4*4+g]; acc += x5 * sWc4[5*4+g];
            ec[g] = elu4(acc);
        }

        int c0 = x_cat[n*3+0], c1 = x_cat[n*3+1], c2 = x_cat[n*3+2];
        int a0 = c0 < 0 ? -c0 : c0;
        int pi = (a0==1)?0:(a0==2)?1:(a0==11)?2:(a0==13)?3:(a0==22)?4:(a0==130)?5:6;
        int ci = c1 + 1;

        f4 t0a = sTc4[ci*2],  t0b = sTc4[ci*2+1];
        f4 t1a = sTp4[pi*2],  t1b = sTp4[pi*2+1];
        f4 t2a = sTv4[c2*2],  t2b = sTv4[c2*2+1];

        f4 ecat[4];
        #pragma unroll
        for (int g = 0; g < 4; g++) {
            f4 acc = sbcat4[g];
            #pragma unroll
            for (int k = 0; k < 4; k++) acc += t0a[k] * sWcat4[(k     )*4+g];
            #pragma unroll
            for (int k = 0; k < 4; k++) acc += t0b[k] * sWcat4[(4 + k )*4+g];
            #pragma unroll
            for (int k = 0; k < 4; k++) acc += t1a[k] * sWcat4[(8 + k )*4+g];
            #pragma unroll
            for (int k = 0; k < 4; k++) acc += t1b[k] * sWcat4[(12 + k)*4+g];
            #pragma unroll
            for (int k = 0; k < 4; k++) acc += t2a[k] * sWcat4[(16 + k)*4+g];
            #pragma unroll
            for (int k = 0; k < 4; k++) acc += t2b[k] * sWcat4[(20 + k)*4+g];
            ecat[g] = elu4(acc);
        }

        f4* o = (f4*)(emb + (size_t)n * 32);
        #pragma unroll
        for (int cg = 0; cg < 8; cg++) {
            f4 acc = sbe4[cg];
            #pragma unroll
            for (int kg = 0; kg < 4; kg++) {
                #pragma unroll
                for (int k = 0; k < 4; k++)
                    acc += ecat[kg][k] * sWe4[(kg*4+k)*8 + cg];
            }
            #pragma unroll
            for (int kg = 0; kg < 4; kg++) {
                #pragma unroll
                for (int k = 0; k < 4; k++)
                    acc += ec[kg][k] * sWe4[(16 + kg*4+k)*8 + cg];
            }
            f4 val = elu4(acc);
            o[cg] = val;
            #pragma unroll
            for (int k = 0; k < 4; k++) {
                v[cg*4+k]      = val[k];
                v[32+cg*4+k]   = val[k] * val[k];
            }
        }
    }

    // multi-value fold reduce: 63 shuffles; lane ends owning index bitrev6(lane)
    #pragma unroll
    for (int st = 0; st < 6; st++) {
        int off = 1 << st;
        int keep = (lane >> st) & 1;
        int L2 = 32 >> st;
        #pragma unroll
        for (int i = 0; i < 32; i++) {
            if (i < L2) {
                float lo = v[i], hi = v[L2 + i];
                float sent = keep ? lo : hi;
                float got = __shfl_xor(sent, off);
                v[i] = (keep ? hi : lo) + got;
            }
        }
    }
    int idx = ((lane&1)<<5)|((lane&2)<<3)|((lane&4)<<1)|((lane&8)>>1)|((lane&16)>>3)|((lane&32)>>5);
    atomicAdd(&sm.e.ls[idx], v[0]);
    __syncthreads();
    if (tid < 64) atomicAdd(&stats[tid], sm.e.ls[tid]);
}

// ---------------- fused B: per-bucket CSR (0..390) | P,Q build (391..781) ----------------
struct SMemCsr { int cnt[256]; int ex[256]; int wsum[4]; int tl; };
struct SMemPq  { float wp[1024], wq[1024], bp[32], bq[32], ssc[32], ssh[32]; };
union SMemB { SMemCsr c; SMemPq q; };

__global__ __launch_bounds__(256) void k_fB(
    const int* __restrict__ curs, const int* __restrict__ pe,
    const int* __restrict__ oflc, const int2* __restrict__ ofl2,
    int* __restrict__ tcur, int2* __restrict__ rowp2, int* __restrict__ srcl,
    const float* __restrict__ emb, const float* __restrict__ stats,
    P19 pp, float* __restrict__ P, unsigned short* __restrict__ Qh)
{
    __shared__ alignas(16) SMemB sm;
    __shared__ int sdet;
    int tid = threadIdx.x;
    int b = blockIdx.x;
    int lane = tid & 63;
    int wid = tid >> 6;

    if (b < NBUCK) {
        int beg = b << CAPSH;
        int m_res = curs[b * CPAD];                  // relative cursor == bucket edge count
        int stored = m_res < CAP ? m_res : CAP;
        int no = oflc[0];                             // overflow entries (normally 0)
        sm.c.cnt[tid] = 0;
        __syncthreads();
        // count pass (pe region is L1/L2-resident for the re-read below)
        for (int i = tid; i < stored; i += 256) {
            int p = pe[beg + i];
            atomicAdd(&sm.c.cnt[p & 255], 1);
        }
        for (int j = tid; j < no; j += 256) {
            int2 oe = ofl2[j];
            if (oe.x == b) atomicAdd(&sm.c.cnt[oe.y & 255], 1);
        }
        __syncthreads();
        // wave-shuffle scan over the 256 per-node counts
        int deg = sm.c.cnt[tid];
        int inc = wave_iscan(deg, lane);
        if (lane == 63) sm.c.wsum[wid] = inc;
        __syncthreads();
        int e0 = inc - deg;
        #pragma unroll
        for (int w = 0; w < 4; w++) if (w < wid) e0 += sm.c.wsum[w];
        int obeg = beg;
        if (m_res > CAP) {                            // astronomically rare: tail-allocate
            if (tid == 0) sm.c.tl = (NBUCK << CAPSH) + atomicAdd(tcur, m_res);
            __syncthreads();
            obeg = sm.c.tl;
        }
        sm.c.ex[tid] = e0;
        int node = b * 256 + tid;
        if (node < NN) rowp2[node] = make_int2(obeg + e0, obeg + e0 + deg);
        sm.c.cnt[tid] = 0;
        __syncthreads();
        // place pass
        for (int i = tid; i < stored; i += 256) {
            int p = pe[beg + i];
            int dl = p & 255;
            int r = atomicAdd(&sm.c.cnt[dl], 1);
            srcl[obeg + sm.c.ex[dl] + r] = p >> 8;
        }
        for (int j = tid; j < no; j += 256) {
            int2 oe = ofl2[j];
            if (oe.x == b) {
                int dl = oe.y & 255;
                int r = atomicAdd(&sm.c.cnt[dl], 1);
                srcl[obeg + sm.c.ex[dl] + r] = oe.y >> 8;
            }
        }
        return;
    }

    // ---- P,Q build (bn1 + Wmsg folded); params converted from raw; Q written as bf16 ----
    int f32 = detect_f32((const unsigned short*)pp.p[7], tid, &sdet);
    if (tid < 32) {
        float mu  = stats[tid] * (1.0f / NN);
        float var = stats[32 + tid] * (1.0f / NN) - mu * mu;
        float s   = ldp(pp.p[9], tid, f32) * rsqrtf(var + 1e-5f);
        sm.q.ssc[tid] = s;
        sm.q.ssh[tid] = ldp(pp.p[10], tid, f32) - mu * s;
    }
    __syncthreads();
    for (int e = tid; e < 1024; e += 256) {
        int k = e >> 5;
        float w1 = ldp(pp.p[11], e, f32);
        float w2 = ldp(pp.p[11], 1024 + e, f32);
        sm.q.wp[e] = sm.q.ssc[k] * (w1 - w2);
        sm.q.wq[e] = sm.q.ssc[k] * w2;
    }
    if (tid < 32) {
        float aP = ldp(pp.p[12], tid, f32), aQ = 0.0f;
        for (int k = 0; k < 32; k++) {
            float w1 = ldp(pp.p[11], k*32 + tid, f32);
            float w2 = ldp(pp.p[11], (k+32)*32 + tid, f32);
            aP += sm.q.ssh[k] * (w1 - w2);
            aQ += sm.q.ssh[k] * w2;
        }
        sm.q.bp[tid] = aP;
        sm.q.bq[tid] = aQ;
    }
    __syncthreads();

    int n = (b - NBUCK) * 256 + tid;
    if (n >= NN) return;

    f4* sWP4 = (f4*)sm.q.wp; f4* sWQ4 = (f4*)sm.q.wq;
    f4* sbP4 = (f4*)sm.q.bp; f4* sbQ4 = (f4*)sm.q.bq;
    const f4* er = (const f4*)(emb + (size_t)n * 32);
    f4 e[8];
    #pragma unroll
    for (int g = 0; g < 8; g++) e[g] = er[g];
    f4* pr = (f4*)(P + (size_t)n * 32);
    uint2* qr = (uint2*)(Qh + (size_t)n * 32);
    #pragma unroll
    for (int cg = 0; cg < 8; cg++) {
        f4 aP = sbP4[cg];
        f4 aQ = sbQ4[cg];
        #pragma unroll
        for (int kg = 0; kg < 8; kg++) {
            #pragma unroll
            for (int k = 0; k < 4; k++) {
                float ek = e[kg][k];
                aP += ek * sWP4[(kg*4+k)*8 + cg];
                aQ += ek * sWQ4[(kg*4+k)*8 + cg];
            }
        }
        pr[cg] = aP;
        uint2 qp;
        qp.x = (unsigned)f2b(aQ.x) | ((unsigned)f2b(aQ.y) << 16);
        qp.y = (unsigned)f2b(aQ.z) | ((unsigned)f2b(aQ.w) << 16);
        qr[cg] = qp;
    }
}

// ---------------- gather-max: 2 nodes per wave; bf16 Q rows (64 B/node) ----------------
__global__ __launch_bounds__(256) void k_gather(
    const int2* __restrict__ rowp2, const int* __restrict__ srcl,
    const unsigned short* __restrict__ Qh, const float* __restrict__ P,
    float* __restrict__ agg)
{
    int tid = threadIdx.x;
    int lane = tid & 63;
    int wave = tid >> 6;
    int half  = lane >> 5;               // which node of the pair
    int hl    = lane & 31;
    int slice = hl >> 3;                 // 0..3 edge slice
    int cg    = hl & 7;                  // channel group
    int n = (blockIdx.x * 4 + wave) * 2 + half;   // 12500 blocks x 4 waves x 2 nodes
    int2 be = rowp2[n];
    int beg = be.x, end = be.y;
    const uint2* Q2 = (const uint2*)Qh;  // 8 uint2 per node row

    // hoisted P read (independent of the edge loop)
    f4 pv = (f4){0.f, 0.f, 0.f, 0.f};
    if (hl < 8 && end > beg) pv = ((const f4*)P)[(size_t)n * 8 + hl];

    f4 m = {-INFINITY, -INFINITY, -INFINITY, -INFINITY};
    // 4 edge-slots per lane per iteration; clamped dup indices are harmless under max
    for (int e = beg + slice; e < end; e += 16) {
        int e1 = min(e + 4,  end - 1);
        int e2 = min(e + 8,  end - 1);
        int e3 = min(e + 12, end - 1);
        int s0 = __builtin_nontemporal_load(&srcl[e]);
        int s1 = __builtin_nontemporal_load(&srcl[e1]);
        int s2 = __builtin_nontemporal_load(&srcl[e2]);
        int s3 = __builtin_nontemporal_load(&srcl[e3]);
        f4 q0 = unpack_q(Q2[(size_t)s0 * 8 + cg]);
        f4 q1 = unpack_q(Q2[(size_t)s1 * 8 + cg]);
        f4 q2 = unpack_q(Q2[(size_t)s2 * 8 + cg]);
        f4 q3 = unpack_q(Q2[(size_t)s3 * 8 + cg]);
        q0 = f4max(q0, q1);
        q2 = f4max(q2, q3);
        m = f4max(m, f4max(q0, q2));
    }
    // reduce across the 4 slices of each half-wave (xor 8, 16 stay within the half)
    #pragma unroll
    for (int off = 8; off < 32; off <<= 1) {
        m.x = fmaxf(m.x, __shfl_xor(m.x, off));
        m.y = fmaxf(m.y, __shfl_xor(m.y, off));
        m.z = fmaxf(m.z, __shfl_xor(m.z, off));
        m.w = fmaxf(m.w, __shfl_xor(m.w, off));
    }
    if (hl < 8) {
        f4 o;
        if (end > beg) o = m + pv;
        else           o = (f4){0.f, 0.f, 0.f, 0.f};
        ((f4*)agg)[(size_t)n * 8 + hl] = o;
    }
}

// ---------------- stats2: per-channel sum & sumsq over agg ----------------
__global__ __launch_bounds__(256) void k_stats(const float* __restrict__ xin,
                                               float* __restrict__ outsums, int count)
{
    __shared__ float ls[64];
    int tid = threadIdx.x;
    if (tid < 64) ls[tid] = 0.0f;
    __syncthreads();
    int idx = blockIdx.x * 256 + tid;
    int stride = gridDim.x * 256;
    int c = idx & 31;
    float s = 0.0f, q = 0.0f;
    for (int i = idx; i < count; i += stride) {
        float v = xin[i];
        s += v; q += v * v;
    }
    s += __shfl_xor(s, 32);
    q += __shfl_xor(q, 32);
    if ((tid & 63) < 32) {
        atomicAdd(&ls[c], s);
        atomicAdd(&ls[32 + c], q);
    }
    __syncthreads();
    if (tid < 64) atomicAdd(&outsums[tid], ls[tid]);
}

// ---------------- output MLP (bn1 & bn2 scales built in-block; raw params) ----------------
__global__ __launch_bounds__(256, 1) void k_out(
    const float* __restrict__ emb, const float* __restrict__ agg,
    P19 pp, const float* __restrict__ stats, void* __restrict__ out)
{
    __shared__ f4 sW14[128];    // [32][16]
    __shared__ f4 sb14[4], sW24[4];
    __shared__ f4 sc14[8], sh14[8], sc24[8], sh24[8];
    __shared__ float sb2s;
    __shared__ int sdet;
    int tid = threadIdx.x;
    int f32 = detect_f32((const unsigned short*)pp.p[7], tid, &sdet);
    {
        float* s = (float*)sW14;
        for (int i = tid; i < 512; i += 256) s[i] = ldp(pp.p[15], i, f32);
    }
    if (tid < 16) {
        ((float*)sb14)[tid] = ldp(pp.p[16], tid, f32);
        ((float*)sW24)[tid] = ldp(pp.p[17], tid, f32);
    }
    if (tid < 32) {
        float mu  = stats[tid] * (1.0f / NN);
        float var = stats[32 + tid] * (1.0f / NN) - mu * mu;
        float s   = ldp(pp.p[9], tid, f32) * rsqrtf(var + 1e-5f);
        ((float*)sc14)[tid] = s;
        ((float*)sh14)[tid] = ldp(pp.p[10], tid, f32) - mu * s;
        float mu2  = stats[64 + tid] * (1.0f / NN);
        float var2 = stats[96 + tid] * (1.0f / NN) - mu2 * mu2;
        float s2   = ldp(pp.p[13], tid, f32) * rsqrtf(var2 + 1e-5f);
        ((float*)sc24)[tid] = s2;
        ((float*)sh24)[tid] = ldp(pp.p[14], tid, f32) - mu2 * s2;
    }
    if (tid == 0) sb2s = ldp(pp.p[18], 0, f32);
    __syncthreads();

    int n = blockIdx.x * 256 + tid;
    if (n >= NN) return;

    const f4* er = (const f4*)(emb + (size_t)n * 32);
    const f4* ar = (const f4*)(agg + (size_t)n * 32);
    f4 h[8];
    #pragma unroll
    for (int g = 0; g < 8; g++) {
        f4 ev = er[g];
        f4 av = ar[g];
        h[g] = ev * sc14[g] + sh14[g] + av * sc24[g] + sh24[g];
    }
    f4 o1[4];
    #pragma unroll
    for (int g = 0; g < 4; g++) {
        f4 acc = sb14[g];
        #pragma unroll
        for (int kg = 0; kg < 8; kg++) {
            #pragma unroll
            for (int k = 0; k < 4; k++)
                acc += h[kg][k] * sW14[(kg*4+k)*4 + g];
        }
        o1[g] = elu4(acc);
    }
    float acc = sb2s;
    #pragma unroll
    for (int g = 0; g < 4; g++) {
        f4 p = o1[g] * sW24[g];
        acc += p.x + p.y + p.z + p.w;
    }

    if (f32) ((float*)out)[n] = acc;
    else     ((bf16_t*)out)[n] = __float2bfloat16(acc);
}

// ======================= launcher (5 dispatches + 1 memset) =======================

extern "C" void kernel_launch(void* const* d_in, const int* in_sizes, int n_in,
                              void* d_out, int out_size, void* d_ws, size_t ws_size,
                              hipStream_t stream)
{
    const void* x_cont = d_in[0];
    const int* x_cat = (const int*)d_in[1];
    const int* eidx  = (const int*)d_in[2];

    float* ws    = (float*)d_ws;
    float* emb   = ws + EMB;
    float* P     = ws + PBUF;
    unsigned short* Qh = (unsigned short*)(ws + QBUF);
    float* agg   = ws + ABUF;
    float* stats = ws + SOFF;
    int*   tcur  = (int*)(stats + 130);
    int*   oflc  = (int*)(stats + 131);
    int*   curs  = (int*)(ws + CURS);
    int2*  rowp2 = (int2*)(ws + ROWP2);
    int2*  ofl2  = (int2*)(ws + OFLB);
    int*   pe    = (int*)(ws + PEB);
    int*   srcl  = (int*)(ws + SRCB);

    P19 pp;
    for (int t = 0; t < 19; t++) pp.p[t] = d_in[4 + t];

    // zero the whole control region: stats(128) + scratch(128) + relative cursors
    hipMemsetAsync(ws + SOFF, 0, (size_t)NZERO * sizeof(float), stream);

    k_fA<<<NPART + NB_SCAN, 256, 0, stream>>>(eidx, curs, pe, oflc, ofl2,
                                              x_cont, x_cat, pp, emb, stats);
    k_fB<<<NBUCK + NB_SCAN, 256, 0, stream>>>(curs, pe, oflc, ofl2, tcur, rowp2, srcl,
                                              emb, stats, pp, P, Qh);
    k_gather<<<NN / 8, 256, 0, stream>>>(rowp2, srcl, Qh, P, agg);
    k_stats<<<512, 256, 0, stream>>>(agg, stats + 64, NN * 32);
    k_out<<<NB_SCAN, 256, 0, stream>>>(emb, agg, pp, stats, d_out);
}